// Round 5
// baseline (332.896 us; speedup 1.0000x reference)
//
#include <hip/hip_runtime.h>
#include <math.h>

// ---------------------------------------------------------------------------
// MPNNPropPred: N=20000 nodes, E=50000 edges, B=128 graphs, H=64,
// FEAT=28, N_TYPES=100, EDGE_DIM=5, MP_ITER=3, S2S_IT=4, OUT=1. All f32.
// R5: MP loop restructured: dense msgall[n][6] = h[n]@{W_t,root} (skinny GEMM,
//     no atomics) + dst-CSR gather aggregation (no atomics). Type-sort gone.
// ---------------------------------------------------------------------------

#define NN 20000
#define NE 50000
#define NB 128
#define HD 64
#define NFEAT 28
#define NTYPES 100
#define EDIM 5
#define MPIT 3
#define S2SIT 4
#define NSL 6                     // 5 edge types + root slice
#define NNB ((NN + 255) / 256)    // 79 blocks over nodes
#define SMAX 224                  // nodes cached in LDS (max graph ~195 expected)
#define HP (HD + 1)               // padded LDS row stride

__device__ __forceinline__ float sigm(float x) {
  return 1.0f / (1.0f + expf(-x));
}

// --- 5 edge-type weight matrices: Wty[t][k*64+o] = relu(W_e1[t]+b_e1) @ W_e2 + b_e2
__global__ void k_edgemats(const float* __restrict__ W_e1, const float* __restrict__ b_e1,
                           const float* __restrict__ W_e2, const float* __restrict__ b_e2,
                           float* __restrict__ Wty) {
  __shared__ float v[HD];
  int t = blockIdx.x >> 2;       // 5 types
  int chunk = blockIdx.x & 3;    // 4 chunks of 1024
  int tid = threadIdx.x;
  if (tid < HD) {
    float x = W_e1[t * HD + tid] + b_e1[tid];
    v[tid] = x > 0.f ? x : 0.f;
  }
  __syncthreads();
  #pragma unroll
  for (int i = 0; i < 4; ++i) {
    int m = chunk * 1024 + i * 256 + tid;
    float acc = b_e2[m];
    #pragma unroll
    for (int j = 0; j < HD; ++j)
      acc = fmaf(v[j], W_e2[j * 4096 + m], acc);
    Wty[t * 4096 + m] = acc;
  }
}

// --- transpose LSTM weights: W_ihT[j][g]=W_ih[g][j] (128x256), W_hhT (64x256)
__global__ void k_wT(const float* __restrict__ W_ih, const float* __restrict__ W_hh,
                     float* __restrict__ W_ihT, float* __restrict__ W_hhT) {
  int idx = blockIdx.x * 256 + threadIdx.x;   // 0..32767
  {
    int g = idx >> 7, j = idx & 127;          // W_ih [256][128]
    W_ihT[j * 256 + g] = W_ih[idx];
  }
  if (idx < 4 * HD * HD) {
    int g = idx >> 6, j = idx & 63;           // W_hh [256][64]
    W_hhT[j * 256 + g] = W_hh[idx];
  }
}

// --- node embedding (uniform feat row via scalar loads)
__global__ void k_embed(const float* __restrict__ feat, const int* __restrict__ ntype,
                        const float* __restrict__ W_emb, const float* __restrict__ b_emb,
                        float* __restrict__ h) {
  int lane = threadIdx.x & 63;
  int n = (blockIdx.x * blockDim.x + threadIdx.x) >> 6;
  if (n >= NN) return;
  int nu = __builtin_amdgcn_readfirstlane(n);
  int t = __builtin_amdgcn_readfirstlane(ntype[nu]);
  const float* row = feat + nu * NFEAT;       // wave-uniform -> s_load
  float acc = b_emb[lane] + W_emb[t * HD + lane];
  #pragma unroll
  for (int f = 0; f < NFEAT; ++f)
    acc = fmaf(row[f], W_emb[(NTYPES + f) * HD + lane], acc);
  h[nu * HD + lane] = acc;
}

// --- dst-CSR build: histogram (20000 bins, low contention) + 3-kernel scan ---
__global__ void k_hist(const int* __restrict__ ei, int* __restrict__ counts) {
  int e = blockIdx.x * 256 + threadIdx.x;
  if (e < NE) atomicAdd(&counts[ei[NE + e]], 1);
}

// per-block exclusive scan of counts, block totals to bsum
__global__ void k_scanA(const int* __restrict__ counts, int* __restrict__ estart,
                        int* __restrict__ bsum) {
  __shared__ int buf[256];
  int tid = threadIdx.x;
  int i = blockIdx.x * 256 + tid;
  int c = (i < NN) ? counts[i] : 0;
  buf[tid] = c;
  __syncthreads();
  #pragma unroll
  for (int off = 1; off < 256; off <<= 1) {
    int x = (tid >= off) ? buf[tid - off] : 0;
    __syncthreads();
    buf[tid] += x;
    __syncthreads();
  }
  if (i < NN) estart[i] = buf[tid] - c;       // exclusive within block
  if (tid == 255) bsum[blockIdx.x] = buf[255];
}

// scan the 79 block sums (single block)
__global__ void k_scanB(int* __restrict__ bsum) {
  __shared__ int buf[128];
  int tid = threadIdx.x;
  int v = (tid < NNB) ? bsum[tid] : 0;
  buf[tid] = v;
  __syncthreads();
  #pragma unroll
  for (int off = 1; off < 128; off <<= 1) {
    int x = (tid >= off) ? buf[tid - off] : 0;
    __syncthreads();
    buf[tid] += x;
    __syncthreads();
  }
  if (tid < NNB) bsum[tid] = buf[tid] - v;    // exclusive
}

// apply block offsets; init cursor; estart[NN]=NE
__global__ void k_scanC(int* __restrict__ estart, const int* __restrict__ bsum,
                        int* __restrict__ cursor) {
  int tid = threadIdx.x;
  int i = blockIdx.x * 256 + tid;
  if (i < NN) {
    int v = estart[i] + bsum[blockIdx.x];
    estart[i] = v;
    cursor[i] = v;
  }
  if (i == 0) estart[NN] = NE;
}

// placement: srcty[pos] = (src<<3)|ty, pos within dst's CSR range
__global__ void k_placed(const int* __restrict__ ei, const int* __restrict__ etype,
                         int* __restrict__ cursor, int* __restrict__ srcty) {
  int e = blockIdx.x * 256 + threadIdx.x;
  if (e >= NE) return;
  int d = ei[NE + e];
  int pos = atomicAdd(&cursor[d], 1);
  srcty[pos] = (ei[e] << 3) | etype[e];
}

// --- CSR starts for sorted batch vector ---
__global__ void k_starts(const int* __restrict__ batch, int* __restrict__ start) {
  int n = blockIdx.x * blockDim.x + threadIdx.x;
  if (n >= NN) return;
  int b = batch[n];
  if (n == 0)
    for (int t = 0; t <= b; ++t) start[t] = 0;
  int bn = (n + 1 < NN) ? batch[n + 1] : NB;
  for (int t = b + 1; t <= bn; ++t) start[t] = n + 1;
}

// --- dense precompute: msgall[n][t][o] = sum_k h[n][k] * W_t[k][o], t=0..4
//     slice 5 = root matrix. Wave holds one W column slice in 64 VGPRs;
//     h rows via wave-uniform scalar loads.
__global__ __launch_bounds__(256) void k_dense(
    const float* __restrict__ h, const float* __restrict__ Wty,
    const float* __restrict__ root, float* __restrict__ msgall) {
  int lane = threadIdx.x & 63;
  int wid = __builtin_amdgcn_readfirstlane(blockIdx.x * 4 + (threadIdx.x >> 6));
  int t = wid >> 10;                 // 6 slices x 1024 waves
  int idx = wid & 1023;
  const float* wsrc = (t < EDIM) ? (Wty + t * 4096) : root;
  float w[HD];
  #pragma unroll
  for (int k = 0; k < HD; ++k) w[k] = wsrc[k * HD + lane];
  for (int n = idx; n < NN; n += 1024) {
    const float* row = h + n * HD;   // wave-uniform -> s_load
    float a0 = 0.f, a1 = 0.f, a2 = 0.f, a3 = 0.f;
    #pragma unroll
    for (int k = 0; k < HD; k += 4) {
      a0 = fmaf(row[k + 0], w[k + 0], a0);
      a1 = fmaf(row[k + 1], w[k + 1], a1);
      a2 = fmaf(row[k + 2], w[k + 2], a2);
      a3 = fmaf(row[k + 3], w[k + 3], a3);
    }
    msgall[n * (NSL * HD) + t * HD + lane] = (a0 + a1) + (a2 + a3);
  }
}

// --- aggregation via dst-CSR gather: hnext[n] = bias + msgall[n][root]
//     + sum_{e: dst=n} msgall[src_e][ty_e]. No atomics.
__global__ __launch_bounds__(256) void k_gather(
    const float* __restrict__ msgall, const int* __restrict__ estart,
    const int* __restrict__ srcty, const float* __restrict__ bias,
    float* __restrict__ hnext) {
  int lane = threadIdx.x & 63;
  int wid = __builtin_amdgcn_readfirstlane(blockIdx.x * 4 + (threadIdx.x >> 6));
  int nw = gridDim.x * 4;
  float bb = bias[lane];
  for (int n = wid; n < NN; n += nw) {
    int s0 = estart[n], e1 = estart[n + 1];   // wave-uniform
    float acc = bb + msgall[n * (NSL * HD) + EDIM * HD + lane];
    int deg = e1 - s0;
    int done = 0;
    while (done < deg) {
      int m = deg - done; if (m > 64) m = 64;
      int v = (lane < m) ? srcty[s0 + done + lane] : 0;  // one coalesced load
      for (int j = 0; j < m; ++j) {
        int u = __builtin_amdgcn_readlane(v, j);
        acc += msgall[(u >> 3) * (NSL * HD) + (u & 7) * HD + lane];
      }
      done += m;
    }
    hnext[n * HD + lane] = acc;
  }
}

// --- Set2Set + output MLP, one block per graph; padded LDS node cache,
//     transposed attention (thread = node, no per-node shuffles).
__global__ __launch_bounds__(256) void k_s2s(
    const float* __restrict__ h, const int* __restrict__ gstart,
    const float* __restrict__ W_ihT, const float* __restrict__ W_hhT,
    const float* __restrict__ b_ih, const float* __restrict__ b_hh,
    const float* __restrict__ W_o1, const float* __restrict__ b_o1,
    const float* __restrict__ W_o2, const float* __restrict__ b_o2,
    float* __restrict__ out) {
  __shared__ float hs[SMAX * HP];     // 58240 B, padded rows
  __shared__ float ebuf[SMAX];
  __shared__ float qstar[2 * HD];
  __shared__ float hxs[HD], cxs[HD], gates[4 * HD];
  __shared__ float redM[4], redS[4], redR[4][HD];
  __shared__ float hid[HD];
  int b = blockIdx.x;
  int tid = threadIdx.x;
  int lane = tid & 63, wv = tid >> 6;
  int st = gstart[b], en = gstart[b + 1];
  int cnt = en - st;
  int cached = cnt < SMAX ? cnt : SMAX;

  // stage node block into padded LDS (coalesced float4 global reads)
  int total = cached * HD;
  for (int base = tid * 4; base < total; base += 1024) {
    float4 v = *reinterpret_cast<const float4*>(h + st * HD + base);
    int n = base >> 6, k = base & 63;
    float* row = hs + n * HP + k;
    row[0] = v.x; row[1] = v.y; row[2] = v.z; row[3] = v.w;
  }
  if (tid < 2 * HD) qstar[tid] = 0.f;
  if (tid < HD) { hxs[tid] = 0.f; cxs[tid] = 0.f; }
  __syncthreads();

  for (int it = 0; it < S2SIT; ++it) {
    // LSTM gates via transposed weights (coalesced): tid = gate index
    float acc0 = b_ih[tid] + b_hh[tid], acc1 = 0.f;
    #pragma unroll 8
    for (int j = 0; j < 2 * HD; j += 2) {
      acc0 = fmaf(qstar[j],     W_ihT[j * 256 + tid],       acc0);
      acc1 = fmaf(qstar[j + 1], W_ihT[(j + 1) * 256 + tid], acc1);
    }
    #pragma unroll 8
    for (int j = 0; j < HD; j += 2) {
      acc0 = fmaf(hxs[j],     W_hhT[j * 256 + tid],       acc0);
      acc1 = fmaf(hxs[j + 1], W_hhT[(j + 1) * 256 + tid], acc1);
    }
    gates[tid] = acc0 + acc1;
    __syncthreads();
    if (tid < HD) {
      float ig = sigm(gates[tid]);
      float fg = sigm(gates[HD + tid]);
      float gg = tanhf(gates[2 * HD + tid]);
      float og = sigm(gates[3 * HD + tid]);
      float c = fmaf(fg, cxs[tid], ig * gg);
      cxs[tid] = c;
      hxs[tid] = og * tanhf(c);
    }
    __syncthreads();

    // pass 1: per-thread dot (thread = node), padded LDS rows (conflict-free)
    float e = -1e30f;
    if (tid < cached) {
      const float* row = hs + tid * HP;
      float d0 = 0.f, d1 = 0.f;
      #pragma unroll 8
      for (int k = 0; k < HD; k += 2) {
        d0 = fmaf(row[k],     hxs[k],     d0);
        d1 = fmaf(row[k + 1], hxs[k + 1], d1);
      }
      e = d0 + d1;
      ebuf[tid] = e;
    }
    float m = e;
    #pragma unroll
    for (int off = 32; off; off >>= 1) m = fmaxf(m, __shfl_xor(m, off, 64));
    float qreg = hxs[lane];
    for (int n = cached + wv; n < cnt; n += 4) {   // overflow tail (normally empty)
      float ev = h[(st + n) * HD + lane] * qreg;
      #pragma unroll
      for (int off = 32; off; off >>= 1) ev += __shfl_xor(ev, off, 64);
      m = fmaxf(m, ev);
    }
    if (lane == 0) redM[wv] = m;
    __syncthreads();
    float M = fmaxf(fmaxf(redM[0], redM[1]), fmaxf(redM[2], redM[3]));

    // pass 2a: a = exp(e-M), per-wave partial sum
    float sp = 0.f;
    if (tid < cached) {
      float a = expf(ebuf[tid] - M);
      ebuf[tid] = a;
      sp = a;
    }
    #pragma unroll
    for (int off = 32; off; off >>= 1) sp += __shfl_xor(sp, off, 64);
    __syncthreads();   // ebuf(a) visible to all waves

    // pass 2b: r = sum_n a[n] * h_n  (lane = feature)
    float r = 0.f;
    for (int n = wv; n < cached; n += 4)
      r = fmaf(ebuf[n], hs[n * HP + lane], r);
    float s_tail = 0.f;
    for (int n = cached + wv; n < cnt; n += 4) {   // overflow tail
      float v = h[(st + n) * HD + lane];
      float ev = v * qreg;
      #pragma unroll
      for (int off = 32; off; off >>= 1) ev += __shfl_xor(ev, off, 64);
      float a = expf(ev - M);
      s_tail += a;
      r = fmaf(a, v, r);
    }
    if (lane == 0) redS[wv] = sp + s_tail;
    redR[wv][lane] = r;
    __syncthreads();
    if (tid < HD) {
      float S = redS[0] + redS[1] + redS[2] + redS[3];
      float R = redR[0][tid] + redR[1][tid] + redR[2][tid] + redR[3][tid];
      if (S == 0.f) S = 1.f;            // empty-graph guard (matches ref)
      qstar[tid] = hxs[tid];
      qstar[HD + tid] = R / S;
    }
    __syncthreads();
  }

  // output MLP: relu(qstar @ W_o1 + b_o1) @ W_o2 + b_o2
  if (tid < HD) {
    float acc = b_o1[tid];
    #pragma unroll 8
    for (int i = 0; i < 2 * HD; ++i)
      acc = fmaf(qstar[i], W_o1[i * HD + tid], acc);
    hid[tid] = acc > 0.f ? acc : 0.f;
  }
  __syncthreads();
  if (tid < HD) {
    float p = hid[tid] * W_o2[tid];
    #pragma unroll
    for (int off = 32; off; off >>= 1) p += __shfl_xor(p, off, 64);
    if (tid == 0) out[b] = p + b_o2[0];
  }
}

extern "C" void kernel_launch(void* const* d_in, const int* in_sizes, int n_in,
                              void* d_out, int out_size, void* d_ws, size_t ws_size,
                              hipStream_t stream) {
  const float* node_feat = (const float*)d_in[0];
  const int*   node_type = (const int*)d_in[1];
  const int*   edge_index= (const int*)d_in[2];
  const int*   edge_type = (const int*)d_in[3];
  const int*   batch     = (const int*)d_in[4];
  const float* W_emb     = (const float*)d_in[5];
  const float* b_emb     = (const float*)d_in[6];
  const float* W_e1      = (const float*)d_in[7];
  const float* b_e1      = (const float*)d_in[8];
  const float* W_e2      = (const float*)d_in[9];
  const float* b_e2      = (const float*)d_in[10];
  const float* roots     = (const float*)d_in[11];
  const float* conv_bias = (const float*)d_in[12];
  const float* W_ih      = (const float*)d_in[13];
  const float* W_hh      = (const float*)d_in[14];
  const float* b_ih      = (const float*)d_in[15];
  const float* b_hh      = (const float*)d_in[16];
  const float* W_o1      = (const float*)d_in[17];
  const float* b_o1      = (const float*)d_in[18];
  const float* W_o2      = (const float*)d_in[19];
  const float* b_o2      = (const float*)d_in[20];
  float* out = (float*)d_out;

  // workspace layout (floats/ints), base assumed 256B-aligned
  float* Wty    = (float*)d_ws;                 // 5*4096
  float* hA     = Wty + EDIM * 4096;            // NN*64
  float* hB     = hA + NN * HD;                 // NN*64
  float* W_ihT  = hB + NN * HD;                 // 128*256
  float* W_hhT  = W_ihT + 2 * HD * 4 * HD;      // 64*256
  float* msgall = W_hhT + HD * 4 * HD;          // NN*384
  int*   counts = (int*)(msgall + NN * NSL * HD); // NN
  int*   estart = counts + NN;                  // NN+1 (pad 8)
  int*   cursor = estart + NN + 8;              // NN
  int*   srcty  = cursor + NN;                  // NE
  int*   bsum   = srcty + NE;                   // NNB (pad 128)
  int*   gstart = bsum + 128;                   // NB+1

  hipMemsetAsync(counts, 0, NN * sizeof(int), stream);

  k_edgemats<<<EDIM * 4, 256, 0, stream>>>(W_e1, b_e1, W_e2, b_e2, Wty);
  k_wT<<<128, 256, 0, stream>>>(W_ih, W_hh, W_ihT, W_hhT);
  k_embed<<<(NN * HD) / 256, 256, 0, stream>>>(node_feat, node_type, W_emb, b_emb, hA);
  k_hist<<<(NE + 255) / 256, 256, 0, stream>>>(edge_index, counts);
  k_scanA<<<NNB, 256, 0, stream>>>(counts, estart, bsum);
  k_scanB<<<1, 128, 0, stream>>>(bsum);
  k_scanC<<<NNB, 256, 0, stream>>>(estart, bsum, cursor);
  k_placed<<<(NE + 255) / 256, 256, 0, stream>>>(edge_index, edge_type, cursor, srcty);
  k_starts<<<(NN + 255) / 256, 256, 0, stream>>>(batch, gstart);

  const float* hcur = hA;
  float* hnxt = hB;
  for (int i = 0; i < MPIT; ++i) {
    k_dense<<<1536, 256, 0, stream>>>(hcur, Wty, roots + i * HD * HD, msgall);
    k_gather<<<1250, 256, 0, stream>>>(msgall, estart, srcty, conv_bias + i * HD, hnxt);
    const float* tmp = hnxt; hnxt = (float*)hcur; hcur = tmp;
  }

  k_s2s<<<NB, 256, 0, stream>>>(hcur, gstart, W_ihT, W_hhT, b_ih, b_hh,
                                W_o1, b_o1, W_o2, b_o2, out);
}